// Round 9
// baseline (501.257 us; speedup 1.0000x reference)
//
#include <hip/hip_runtime.h>
#include <stdint.h>

typedef __attribute__((ext_vector_type(4))) int i32x4;
typedef __attribute__((ext_vector_type(4))) float f32x4v;

#define EPSQ 1e-5f

__device__ __forceinline__ void async_copy16(const void* g, void* l) {
  __builtin_amdgcn_global_load_lds(
      (const __attribute__((address_space(1))) unsigned int*)g,
      (__attribute__((address_space(3))) unsigned int*)l,
      16, 0, 0);
}

// quantize 4 floats -> 4 packed int8 codes (two's complement)
__device__ __forceinline__ unsigned pack4_q(float x, float y, float z, float w,
                                            float scale, float lo, float hi) {
  int q0 = (int)fminf(fmaxf(rintf(x * scale), lo), hi);
  int q1 = (int)fminf(fmaxf(rintf(y * scale), lo), hi);
  int q2 = (int)fminf(fmaxf(rintf(z * scale), lo), hi);
  int q3 = (int)fminf(fmaxf(rintf(w * scale), lo), hi);
  return (unsigned)(q0 & 255) | ((unsigned)(q1 & 255) << 8) |
         ((unsigned)(q2 & 255) << 16) | ((unsigned)(q3 & 255) << 24);
}

// ---------------- W absmean reduction (double accumulation) ----------------
__global__ __launch_bounds__(256) void abssum_kernel(const float4* __restrict__ W,
                                                     double* __restrict__ sum, int n4) {
  __shared__ double red[4];
  double acc = 0.0;
  int stride = gridDim.x * blockDim.x;
  for (int v = blockIdx.x * blockDim.x + threadIdx.x; v < n4; v += stride) {
    float4 p = W[v];
    acc += (double)fabsf(p.x) + (double)fabsf(p.y) +
           (double)fabsf(p.z) + (double)fabsf(p.w);
  }
  for (int off = 32; off > 0; off >>= 1) acc += __shfl_down(acc, off);
  if ((threadIdx.x & 63) == 0) red[threadIdx.x >> 6] = acc;
  __syncthreads();
  if (threadIdx.x == 0)
    atomicAdd(sum, (red[0] + red[1]) + (red[2] + red[3]));
}

// ---------------- finalize scalars + A_eff ----------------
// scalf layout: [0..1]=double sum|W|, [2]=mw (dequant), [3]=sw=1/mw (quant)
__global__ void finalize_kernel(const float* __restrict__ A_raw, float* __restrict__ scalf,
                                float* __restrict__ a_eff, int D, double inv_cnt) {
  int i = blockIdx.x * blockDim.x + threadIdx.x;
  if (i < D) a_eff[i] = 0.99f * tanhf(A_raw[i]);
  if (i == 0) {
    double s = *(const double*)scalf;
    float mw = fmaxf((float)(s * inv_cnt), EPSQ);  // clip(mean|W|, EPS)
    scalf[2] = mw;
    scalf[3] = 1.0f / mw;
  }
}

// ---------------- ternary quantize W -> int8 codes {-1,0,1} ----------------
__global__ __launch_bounds__(256) void quantw_kernel(const float4* __restrict__ W,
                                                     unsigned* __restrict__ Wq,
                                                     const float* __restrict__ scalf, int n4) {
  float sw = scalf[3];
  int base = blockIdx.x * 1024 + threadIdx.x;
#pragma unroll
  for (int j = 0; j < 4; ++j) {
    int idx = base + 256 * j;
    if (idx < n4) {
      float4 p = W[idx];
      Wq[idx] = pack4_q(p.x, p.y, p.z, p.w, sw, -1.f, 1.f);
    }
  }
}

// ---------------- per-token int8 quant of e -> int8 codes [-127,127] -------
__global__ __launch_bounds__(256) void quante_kernel(const float* __restrict__ E,
                                                     char* __restrict__ Eq,
                                                     float* __restrict__ rowscale, int K) {
  int wave = threadIdx.x >> 6;
  int lane = threadIdx.x & 63;
  int row = blockIdx.x * 4 + wave;
  const float4* src = (const float4*)(E + (size_t)row * K);
  float4 v[8];  // K=2048: 512 float4/row = 64 lanes x 8
#pragma unroll
  for (int j = 0; j < 8; ++j) v[j] = src[lane + 64 * j];
  float amax = 0.f;
#pragma unroll
  for (int j = 0; j < 8; ++j)
    amax = fmaxf(amax, fmaxf(fmaxf(fabsf(v[j].x), fabsf(v[j].y)),
                             fmaxf(fabsf(v[j].z), fabsf(v[j].w))));
#pragma unroll
  for (int off = 32; off > 0; off >>= 1) amax = fmaxf(amax, __shfl_xor(amax, off));
  float clipped = fmaxf(amax, EPSQ);
  float scale = 127.0f / clipped;  // matches jax: 127/clip(max|x|,EPS)
  unsigned* dst = (unsigned*)(Eq + (size_t)row * K);
#pragma unroll
  for (int j = 0; j < 8; ++j)
    dst[lane + 64 * j] = pack4_q(v[j].x, v[j].y, v[j].z, v[j].w, scale, -128.f, 127.f);
  if (lane == 0) rowscale[row] = clipped / 127.0f;  // == 1/scale to 2^-24
}

// ---------------- 256x256x128 int8 MFMA GEMM, counted-vmcnt pipeline -------
// K-loop identical to R7 (verified). Epilogue: in-register 4x4 quad
// transpose of each C fragment (8 shfl_xor + 8 selects; verified
// symbolically: c[k]^(q) = r[q]^(k)) so each lane owns one row x 4
// consecutive cols -> 16B h/bo loads + 16B out stores: 96 VMEM
// instrs/thread instead of 384 scalar-dword ones. nontemporal on stores
// only (ext_vector type: __builtin_nontemporal_store rejects
// HIP_vector_type — R8 compile fix).
__global__ __launch_bounds__(512) void gemm_kernel(
    const char* __restrict__ Eq, const char* __restrict__ Wq,
    const float* __restrict__ h, const float* __restrict__ bo,
    const float* __restrict__ a_eff, const float* __restrict__ rowscale,
    const float* __restrict__ scalf, float* __restrict__ out,
    int M, int N, int K) {
  __shared__ __attribute__((aligned(16))) char As[2][256 * 128];
  __shared__ __attribute__((aligned(16))) char Bs[2][256 * 128];

  int tid = threadIdx.x;
  int lane = tid & 63;
  int wave = tid >> 6;
  int wm = wave >> 2, wn = wave & 3;

  // T1: XCD-aware bijective remap. grid = 512 = 8 XCD * 64 tiles.
  int bid = blockIdx.x;
  int wgid = (bid & 7) * 64 + (bid >> 3);
  int n0 = (wgid & 7) * 256;     // N/256 = 8 n-panels, n-fastest
  int m0 = (wgid >> 3) * 256;

  // staging: 2048 16B-chunks per matrix (256 rows x 8); thread t, round r
  // covers chunk c = t + 512r -> row = (t>>3)+64r, chunk-col cc = t&7.
  // lds linear (global_load_lds requirement); global source inverse-swizzled:
  // gcc = cc ^ (row&7)  (round-invariant: rows advance by 64 == 0 mod 8).
  int srow = tid >> 3;
  int gcc = (tid & 7) ^ (srow & 7);

  const char* ga = Eq + (size_t)(m0 + srow) * K + gcc * 16;
  const char* gb = Wq + (size_t)(n0 + srow) * K + gcc * 16;

  i32x4 acc[8][4] = {};

  int lm = lane & 15;
  int kg = lane >> 4;        // 4 K-groups of 16 bytes per 64-elem MFMA step
  int xr = lm & 7;           // read-side swizzle (row&7 == lm&7 for our rows)
  int arow_off = (wm * 128 + lm) * 128;
  int brow_off = (wn * 64 + lm) * 128;

#define STAGE(b)                                                    \
  do {                                                              \
    char* la_ = As[b] + tid * 16;                                   \
    char* lb_ = Bs[b] + tid * 16;                                   \
    _Pragma("unroll") for (int r_ = 0; r_ < 4; ++r_) {              \
      async_copy16(ga + (size_t)(64 * r_) * K, la_ + 8192 * r_);    \
      async_copy16(gb + (size_t)(64 * r_) * K, lb_ + 8192 * r_);    \
    }                                                               \
    ga += 128; gb += 128;                                           \
  } while (0)

#define COMPUTE(b)                                                            \
  do {                                                                        \
    const char* arow_ = As[b] + arow_off;                                     \
    const char* brow_ = Bs[b] + brow_off;                                     \
    _Pragma("unroll") for (int ks = 0; ks < 2; ++ks) {                        \
      int ccA = ((ks * 4 + kg) ^ xr) * 16;                                    \
      i32x4 af[8], bg[4];                                                     \
      _Pragma("unroll") for (int i = 0; i < 8; ++i)                           \
        af[i] = *(const i32x4*)(arow_ + i * 16 * 128 + ccA);                  \
      _Pragma("unroll") for (int j = 0; j < 4; ++j)                           \
        bg[j] = *(const i32x4*)(brow_ + j * 16 * 128 + ccA);                  \
      _Pragma("unroll") for (int i = 0; i < 8; ++i)                           \
        _Pragma("unroll") for (int j = 0; j < 4; ++j)                         \
          acc[i][j] =                                                         \
              __builtin_amdgcn_mfma_i32_16x16x64_i8(af[i], bg[j], acc[i][j],  \
                                                    0, 0, 0);                 \
    }                                                                         \
  } while (0)

// counted wait: retire down to N outstanding VMEM ops, then raw barrier.
// sched_barrier(0) on both sides pins code motion across the sync point.
#define WAITBAR(N)                                                  \
  do {                                                              \
    __builtin_amdgcn_sched_barrier(0);                              \
    asm volatile("s_waitcnt vmcnt(" #N ")" ::: "memory");           \
    __builtin_amdgcn_s_barrier();                                   \
    __builtin_amdgcn_sched_barrier(0);                              \
  } while (0)

#define BAR()                                                       \
  do {                                                              \
    __builtin_amdgcn_sched_barrier(0);                              \
    __builtin_amdgcn_s_barrier();                                   \
    __builtin_amdgcn_sched_barrier(0);                              \
  } while (0)

  // prologue: stage tiles 0 and 1 (16 loads in flight)
  STAGE(0);
  STAGE(1);

  // steady state, 2 tiles per iteration (static buffer indices):
  // wait t (leave t+1 flying) -> compute t -> fence readers -> stage t+2.
  int ktiles = K / 128;      // 16
  for (int kt = 0; kt < ktiles - 2; kt += 2) {
    WAITBAR(8);     // tile kt's 8 retired; tile kt+1's 8 fly under COMPUTE
    COMPUTE(0);
    BAR();          // all waves done reading buf0 before re-stage
    STAGE(0);       // tile kt+2 -> 16 outstanding again
    WAITBAR(8);
    COMPUTE(1);
    BAR();
    STAGE(1);       // tile kt+3
  }
  // tail: tiles ktiles-2 (buf0), ktiles-1 (buf1) staged, 16 outstanding
  WAITBAR(8);
  COMPUTE(0);
  WAITBAR(0);       // drain last tile's loads
  COMPUTE(1);

  // ---- epilogue: quad-transposed, 16B vector ----
  // C/D layout: col=lane&15, row=(lane>>4)*4+reg [m89/m91]. Within each
  // 4-lane quad (cols colq..colq+3, regs=4 rows), transpose so lane q owns
  // row r4+q with regs = 4 consecutive cols. Verified: c[k]^(q)=r[q]^(k).
  float mw = scalf[2];
  int q = lane & 3;
  int r4 = (lane >> 4) * 4;
  int colq = lm & ~3;                      // 0,4,8,12
  int nbase = n0 + wn * 64 + colq;
  f32x4v aeff4[4];
#pragma unroll
  for (int j = 0; j < 4; ++j) aeff4[j] = *(const f32x4v*)&a_eff[nbase + j * 16];
#pragma unroll
  for (int i = 0; i < 8; ++i) {
    int row = m0 + wm * 128 + i * 16 + r4 + q;
    float sm = rowscale[row] * mw;
    size_t ro = (size_t)row * N + nbase;
#pragma unroll
    for (int j = 0; j < 4; ++j) {
      float r0 = (float)acc[i][j][0], r1 = (float)acc[i][j][1],
            r2 = (float)acc[i][j][2], r3 = (float)acc[i][j][3];
      // stage 1: swap bit0 of (reg,quad-lane)
      float p0 = __shfl_xor(r0, 1), p1 = __shfl_xor(r1, 1),
            p2 = __shfl_xor(r2, 1), p3 = __shfl_xor(r3, 1);
      bool o1 = q & 1;
      float b0 = o1 ? p1 : r0, b1 = o1 ? r1 : p0,
            b2 = o1 ? p3 : r2, b3 = o1 ? r3 : p2;
      // stage 2: swap bit1
      float P0 = __shfl_xor(b0, 2), P1 = __shfl_xor(b1, 2),
            P2 = __shfl_xor(b2, 2), P3 = __shfl_xor(b3, 2);
      bool o2 = q & 2;
      float c0 = o2 ? P2 : b0, c1 = o2 ? P3 : b1,
            c2 = o2 ? b2 : P0, c3 = o2 ? b3 : P1;
      f32x4v h4 = *(const f32x4v*)&h[ro + j * 16];
      f32x4v b4 = *(const f32x4v*)&bo[ro + j * 16];
      f32x4v o4;
      o4.x = fmaf(c0, sm, fmaf(aeff4[j].x, h4.x, b4.x));
      o4.y = fmaf(c1, sm, fmaf(aeff4[j].y, h4.y, b4.y));
      o4.z = fmaf(c2, sm, fmaf(aeff4[j].z, h4.z, b4.z));
      o4.w = fmaf(c3, sm, fmaf(aeff4[j].w, h4.w, b4.w));
      __builtin_nontemporal_store(o4, (f32x4v*)&out[ro + j * 16]);
    }
  }
#undef STAGE
#undef COMPUTE
#undef WAITBAR
#undef BAR
}

extern "C" void kernel_launch(void* const* d_in, const int* in_sizes, int n_in,
                              void* d_out, int out_size, void* d_ws, size_t ws_size,
                              hipStream_t stream) {
  const float* h_p   = (const float*)d_in[0];
  const float* e_p   = (const float*)d_in[1];
  const float* bo_p  = (const float*)d_in[2];
  const float* A_raw = (const float*)d_in[3];
  const float* W_p   = (const float*)d_in[4];
  float* out = (float*)d_out;

  int D = in_sizes[3];        // 2048
  int M = in_sizes[0] / D;    // 16384
  int N = D, K = D;

  char* ws = (char*)d_ws;
  float* scalf     = (float*)ws;                       // [0..1]=dbl sum, [2]=mw, [3]=sw
  float* a_eff     = (float*)(ws + 4096);              // D floats
  float* rowscale  = (float*)(ws + 65536);             // M floats (64 KB)
  char* Wq         = ws + 131072;                      // N*K int8 codes (4 MB)
  char* Eq         = ws + 131072 + (size_t)N * K;      // M*K int8 codes (32 MB)

  hipMemsetAsync(d_ws, 0, 64, stream);
  int nW = N * K;
  abssum_kernel<<<256, 256, 0, stream>>>((const float4*)W_p, (double*)scalf, nW / 4);
  finalize_kernel<<<(D + 255) / 256, 256, 0, stream>>>(A_raw, scalf, a_eff, D,
                                                       1.0 / (double)nW);
  quantw_kernel<<<(nW / 4 + 1023) / 1024, 256, 0, stream>>>((const float4*)W_p,
                                                            (unsigned*)Wq, scalf, nW / 4);
  quante_kernel<<<M / 4, 256, 0, stream>>>(e_p, Eq, rowscale, K);
  int nwg = (N / 256) * (M / 256);   // 512, %8 == 0 -> bijective XCD swizzle
  gemm_kernel<<<nwg, 512, 0, stream>>>(Eq, Wq, h_p, bo_p, a_eff, rowscale, scalf, out,
                                       M, N, K);
}

// Round 10
// 472.096 us; speedup vs baseline: 1.0618x; 1.0618x over previous
//
#include <hip/hip_runtime.h>
#include <stdint.h>

typedef __attribute__((ext_vector_type(4))) int i32x4;

#define EPSQ 1e-5f

__device__ __forceinline__ void async_copy16(const void* g, void* l) {
  __builtin_amdgcn_global_load_lds(
      (const __attribute__((address_space(1))) unsigned int*)g,
      (__attribute__((address_space(3))) unsigned int*)l,
      16, 0, 0);
}

// quantize 4 floats -> 4 packed int8 codes (two's complement)
__device__ __forceinline__ unsigned pack4_q(float x, float y, float z, float w,
                                            float scale, float lo, float hi) {
  int q0 = (int)fminf(fmaxf(rintf(x * scale), lo), hi);
  int q1 = (int)fminf(fmaxf(rintf(y * scale), lo), hi);
  int q2 = (int)fminf(fmaxf(rintf(z * scale), lo), hi);
  int q3 = (int)fminf(fmaxf(rintf(w * scale), lo), hi);
  return (unsigned)(q0 & 255) | ((unsigned)(q1 & 255) << 8) |
         ((unsigned)(q2 & 255) << 16) | ((unsigned)(q3 & 255) << 24);
}

// ---------------- W absmean reduction (double accumulation) ----------------
__global__ __launch_bounds__(256) void abssum_kernel(const float4* __restrict__ W,
                                                     double* __restrict__ sum, int n4) {
  __shared__ double red[4];
  double acc = 0.0;
  int stride = gridDim.x * blockDim.x;
  for (int v = blockIdx.x * blockDim.x + threadIdx.x; v < n4; v += stride) {
    float4 p = W[v];
    acc += (double)fabsf(p.x) + (double)fabsf(p.y) +
           (double)fabsf(p.z) + (double)fabsf(p.w);
  }
  for (int off = 32; off > 0; off >>= 1) acc += __shfl_down(acc, off);
  if ((threadIdx.x & 63) == 0) red[threadIdx.x >> 6] = acc;
  __syncthreads();
  if (threadIdx.x == 0)
    atomicAdd(sum, (red[0] + red[1]) + (red[2] + red[3]));
}

// ---------------- finalize scalars + A_eff ----------------
// scalf layout: [0..1]=double sum|W|, [2]=mw (dequant), [3]=sw=1/mw (quant)
__global__ void finalize_kernel(const float* __restrict__ A_raw, float* __restrict__ scalf,
                                float* __restrict__ a_eff, int D, double inv_cnt) {
  int i = blockIdx.x * blockDim.x + threadIdx.x;
  if (i < D) a_eff[i] = 0.99f * tanhf(A_raw[i]);
  if (i == 0) {
    double s = *(const double*)scalf;
    float mw = fmaxf((float)(s * inv_cnt), EPSQ);  // clip(mean|W|, EPS)
    scalf[2] = mw;
    scalf[3] = 1.0f / mw;
  }
}

// ---------------- ternary quantize W -> int8 codes {-1,0,1} ----------------
__global__ __launch_bounds__(256) void quantw_kernel(const float4* __restrict__ W,
                                                     unsigned* __restrict__ Wq,
                                                     const float* __restrict__ scalf, int n4) {
  float sw = scalf[3];
  int base = blockIdx.x * 1024 + threadIdx.x;
#pragma unroll
  for (int j = 0; j < 4; ++j) {
    int idx = base + 256 * j;
    if (idx < n4) {
      float4 p = W[idx];
      Wq[idx] = pack4_q(p.x, p.y, p.z, p.w, sw, -1.f, 1.f);
    }
  }
}

// ---------------- per-token int8 quant of e -> int8 codes [-127,127] -------
__global__ __launch_bounds__(256) void quante_kernel(const float* __restrict__ E,
                                                     char* __restrict__ Eq,
                                                     float* __restrict__ rowscale, int K) {
  int wave = threadIdx.x >> 6;
  int lane = threadIdx.x & 63;
  int row = blockIdx.x * 4 + wave;
  const float4* src = (const float4*)(E + (size_t)row * K);
  float4 v[8];  // K=2048: 512 float4/row = 64 lanes x 8
#pragma unroll
  for (int j = 0; j < 8; ++j) v[j] = src[lane + 64 * j];
  float amax = 0.f;
#pragma unroll
  for (int j = 0; j < 8; ++j)
    amax = fmaxf(amax, fmaxf(fmaxf(fabsf(v[j].x), fabsf(v[j].y)),
                             fmaxf(fabsf(v[j].z), fabsf(v[j].w))));
#pragma unroll
  for (int off = 32; off > 0; off >>= 1) amax = fmaxf(amax, __shfl_xor(amax, off));
  float clipped = fmaxf(amax, EPSQ);
  float scale = 127.0f / clipped;  // matches jax: 127/clip(max|x|,EPS)
  unsigned* dst = (unsigned*)(Eq + (size_t)row * K);
#pragma unroll
  for (int j = 0; j < 8; ++j)
    dst[lane + 64 * j] = pack4_q(v[j].x, v[j].y, v[j].z, v[j].w, scale, -128.f, 127.f);
  if (lane == 0) rowscale[row] = clipped / 127.0f;  // == 1/scale to 2^-24
}

// ---------------- 256x256x64 int8 MFMA GEMM, counted-vmcnt, 2 blocks/CU ----
// R9 post-mortem: quad-transpose epilogue regressed (WRITE +33MB from broken
// write-combining; 256 ds_bpermute on the LDS pipe) -> epilogue reverted to
// the R7-verified scalar form. The 1-block/CU kernel is PHASE-SERIALIZED
// (MFMA idle during ~72us epilogue stream, HBM idle during K-loop); fix is
// co-residency: BK=64 -> LDS 64KB -> 2 blocks/CU (512 blocks / 256 CU), so
// one block's K-loop overlaps the other's epilogue (m114 mechanism).
// Counted-vmcnt skeleton unchanged (R6-verified), N=4: each STAGE issues
// exactly 4 global_load_lds per thread. Swizzle = R5-measured-0-conflict
// BK=64 form: stage gcc=(tid&3)^((srow>>1)&3); read ccA=(kg^((lm>>1)&3))*16
// (round-invariant: rows advance by 128 == 0 mod 8).
__global__ __launch_bounds__(512) void gemm_kernel(
    const char* __restrict__ Eq, const char* __restrict__ Wq,
    const float* __restrict__ h, const float* __restrict__ bo,
    const float* __restrict__ a_eff, const float* __restrict__ rowscale,
    const float* __restrict__ scalf, float* __restrict__ out,
    int M, int N, int K) {
  __shared__ __attribute__((aligned(16))) char As[2][256 * 64];
  __shared__ __attribute__((aligned(16))) char Bs[2][256 * 64];

  int tid = threadIdx.x;
  int lane = tid & 63;
  int wave = tid >> 6;
  int wm = wave >> 2, wn = wave & 3;

  // T1: XCD-aware bijective remap. grid = 512 = 8 XCD * 64 tiles.
  int bid = blockIdx.x;
  int wgid = (bid & 7) * 64 + (bid >> 3);
  int n0 = (wgid & 7) * 256;     // N/256 = 8 n-panels, n-fastest
  int m0 = (wgid >> 3) * 256;

  // staging: 1024 16B-chunks per matrix (256 rows x 4); thread t, round r
  // covers chunk c = t + 512r -> row = (t>>2)+128r, chunk-col cc = t&3.
  // lds linear (global_load_lds requirement); global source inverse-swizzled.
  int srow = tid >> 2;
  int gcc = (tid & 3) ^ ((srow >> 1) & 3);

  const char* ga = Eq + (size_t)(m0 + srow) * K + gcc * 16;
  const char* gb = Wq + (size_t)(n0 + srow) * K + gcc * 16;

  i32x4 acc[8][4] = {};

  int lm = lane & 15;
  int kg = lane >> 4;            // 4 K-groups of 16B = one 64-elem MFMA step
  int xr = (lm >> 1) & 3;        // read-side swizzle: (row>>1)&3 == (lm>>1)&3
  int arow_off = (wm * 128 + lm) * 64;
  int brow_off = (wn * 64 + lm) * 64;
  int ccA = (kg ^ xr) * 16;

#define STAGE(b)                                                    \
  do {                                                              \
    char* la_ = As[b] + tid * 16;                                   \
    char* lb_ = Bs[b] + tid * 16;                                   \
    _Pragma("unroll") for (int r_ = 0; r_ < 2; ++r_) {              \
      async_copy16(ga + (size_t)(128 * r_) * K, la_ + 8192 * r_);   \
      async_copy16(gb + (size_t)(128 * r_) * K, lb_ + 8192 * r_);   \
    }                                                               \
    ga += 64; gb += 64;                                             \
  } while (0)

#define COMPUTE(b)                                                            \
  do {                                                                        \
    const char* arow_ = As[b] + arow_off;                                     \
    const char* brow_ = Bs[b] + brow_off;                                     \
    i32x4 af[8], bg[4];                                                       \
    _Pragma("unroll") for (int i = 0; i < 8; ++i)                             \
      af[i] = *(const i32x4*)(arow_ + i * 16 * 64 + ccA);                     \
    _Pragma("unroll") for (int j = 0; j < 4; ++j)                             \
      bg[j] = *(const i32x4*)(brow_ + j * 16 * 64 + ccA);                     \
    _Pragma("unroll") for (int i = 0; i < 8; ++i)                             \
      _Pragma("unroll") for (int j = 0; j < 4; ++j)                           \
        acc[i][j] =                                                           \
            __builtin_amdgcn_mfma_i32_16x16x64_i8(af[i], bg[j], acc[i][j],    \
                                                  0, 0, 0);                   \
  } while (0)

// counted wait: retire down to N outstanding VMEM ops, then raw barrier.
// sched_barrier(0) on both sides pins code motion across the sync point.
#define WAITBAR(N)                                                  \
  do {                                                              \
    __builtin_amdgcn_sched_barrier(0);                              \
    asm volatile("s_waitcnt vmcnt(" #N ")" ::: "memory");           \
    __builtin_amdgcn_s_barrier();                                   \
    __builtin_amdgcn_sched_barrier(0);                              \
  } while (0)

#define BAR()                                                       \
  do {                                                              \
    __builtin_amdgcn_sched_barrier(0);                              \
    __builtin_amdgcn_s_barrier();                                   \
    __builtin_amdgcn_sched_barrier(0);                              \
  } while (0)

  // prologue: stage tiles 0 and 1 (8 loads in flight)
  STAGE(0);
  STAGE(1);

  // steady state, 2 tiles per iteration (static buffer indices):
  // wait t (leave t+1 flying) -> compute t -> fence readers -> stage t+2.
  int ktiles = K / 64;       // 32
  for (int kt = 0; kt < ktiles - 2; kt += 2) {
    WAITBAR(4);     // tile kt's 4 retired; tile kt+1's 4 fly under COMPUTE
    COMPUTE(0);
    BAR();          // all waves done reading buf0 before re-stage
    STAGE(0);       // tile kt+2 -> 8 outstanding again
    WAITBAR(4);
    COMPUTE(1);
    BAR();
    STAGE(1);       // tile kt+3
  }
  // tail: tiles ktiles-2 (buf0), ktiles-1 (buf1) staged, 8 outstanding
  WAITBAR(4);
  COMPUTE(0);
  WAITBAR(0);       // drain last tile's loads
  COMPUTE(1);

  // ---- epilogue: R7-verified scalar form ----
  // C/D layout col=lane&15 (n), row=(lane>>4)*4+reg  [m89/m91]
  float mw = scalf[2];
  int r4 = (lane >> 4) * 4;
  float aeffj[4];
#pragma unroll
  for (int j = 0; j < 4; ++j) aeffj[j] = a_eff[n0 + wn * 64 + j * 16 + lm];
#pragma unroll
  for (int i = 0; i < 8; ++i) {
    int mb = m0 + wm * 128 + i * 16 + r4;
#pragma unroll
    for (int r = 0; r < 4; ++r) {
      size_t ro = (size_t)(mb + r) * N;
      float sm = rowscale[mb + r] * mw;
#pragma unroll
      for (int j = 0; j < 4; ++j) {
        int n = n0 + wn * 64 + j * 16 + lm;
        float hv = __builtin_nontemporal_load(&h[ro + n]);
        float bv = __builtin_nontemporal_load(&bo[ro + n]);
        float val = fmaf((float)acc[i][j][r], sm, fmaf(aeffj[j], hv, bv));
        __builtin_nontemporal_store(val, &out[ro + n]);
      }
    }
  }
#undef STAGE
#undef COMPUTE
#undef WAITBAR
#undef BAR
}

extern "C" void kernel_launch(void* const* d_in, const int* in_sizes, int n_in,
                              void* d_out, int out_size, void* d_ws, size_t ws_size,
                              hipStream_t stream) {
  const float* h_p   = (const float*)d_in[0];
  const float* e_p   = (const float*)d_in[1];
  const float* bo_p  = (const float*)d_in[2];
  const float* A_raw = (const float*)d_in[3];
  const float* W_p   = (const float*)d_in[4];
  float* out = (float*)d_out;

  int D = in_sizes[3];        // 2048
  int M = in_sizes[0] / D;    // 16384
  int N = D, K = D;

  char* ws = (char*)d_ws;
  float* scalf     = (float*)ws;                       // [0..1]=dbl sum, [2]=mw, [3]=sw
  float* a_eff     = (float*)(ws + 4096);              // D floats
  float* rowscale  = (float*)(ws + 65536);             // M floats (64 KB)
  char* Wq         = ws + 131072;                      // N*K int8 codes (4 MB)
  char* Eq         = ws + 131072 + (size_t)N * K;      // M*K int8 codes (32 MB)

  hipMemsetAsync(d_ws, 0, 64, stream);
  int nW = N * K;
  abssum_kernel<<<256, 256, 0, stream>>>((const float4*)W_p, (double*)scalf, nW / 4);
  finalize_kernel<<<(D + 255) / 256, 256, 0, stream>>>(A_raw, scalf, a_eff, D,
                                                       1.0 / (double)nW);
  quantw_kernel<<<(nW / 4 + 1023) / 1024, 256, 0, stream>>>((const float4*)W_p,
                                                            (unsigned*)Wq, scalf, nW / 4);
  quante_kernel<<<M / 4, 256, 0, stream>>>(e_p, Eq, rowscale, K);
  int nwg = (N / 256) * (M / 256);   // 512, %8 == 0 -> bijective XCD swizzle
  gemm_kernel<<<nwg, 512, 0, stream>>>(Eq, Wq, h_p, bo_p, a_eff, rowscale, scalf, out,
                                       M, N, K);
}